// Round 5
// baseline (31.326 us; speedup 1.0000x reference)
//
#include <hip/hip_runtime.h>

// LIF scan, x (B=32,G=4,T=512,C=256) f32 -> 32768 independent chains (one per
// thread), T sequential. Memory-bound: 67 MB read + 67 MB write.
//
// R5 = R4 with the compile fix (ext_vector_type for nontemporal x4 store).
//  - Exact simplified recurrence (R always {0,1}):
//      Vm' = (Vm >= 1) ? 0 : (w*xt + a*Vm)     [contract off, numpy op order]
//  - Register prefetch ring D=64: effective latency coverage ~50
//    load-intervals after the vmcnt-63 clamp (~1500+ cycles).
//  - LDS store-transpose -> nontemporal dwordx4 store every 4 steps.
//  - Nontemporal loads/stores: both streams are touch-once, skip L2 fill.
//  - XCD swizzle: the 4 channel-slice blocks of sequence n share XCD n%8.

typedef float f32x4 __attribute__((ext_vector_type(4)));

constexpr int T_STEPS = 512;
constexpr int CCH     = 256;
constexpr int NSEQ    = 128;   // B*G
constexpr int D       = 64;    // prefetch ring depth (T_STEPS % D == 0)
constexpr int CB      = 64;    // channels per block

__global__ __launch_bounds__(64, 1) void lif_kernel(
    const float* __restrict__ x,
    const float* __restrict__ w_input,
    const float* __restrict__ w_leak,
    float* __restrict__ out)
{
#pragma clang fp contract(off)
    __shared__ float obuf[4 * CB];          // 1 KB store-transpose staging

    const int lane = threadIdx.x;
    const int b    = blockIdx.x;
    // swizzle: the 4 channel-slices of sequence n land on XCD n%8
    const int n  = (b & 7) + ((b >> 5) << 3);
    const int cb = ((b >> 3) & 3) << 6;

    const int ch = cb + lane;
    const float w = w_input[ch];
    const float a = 1.0f - w_leak[ch];

    const float* xp = x + (size_t)n * T_STEPS * CCH + ch;     // scalar load base
    // x4 store base: lane i covers t-offset (i>>4), channels 4*(i&15)..+3
    float* go = out + (size_t)n * T_STEPS * CCH + cb + (lane >> 4) * CCH + 4 * (lane & 15);

    // Prime the ring: x[0..D-1]
    float buf[D];
#pragma unroll
    for (int d0 = 0; d0 < D; ++d0)
        buf[d0] = __builtin_nontemporal_load(xp + (size_t)d0 * CCH);

    float Vm = 0.0f;

    // Main loop: consume buf[k] (loaded D steps ago), refill with x[t+D].
    for (int t0 = 0; t0 < T_STEPS - D; t0 += D) {
#pragma unroll
        for (int k = 0; k < D; ++k) {
            const float xt = buf[k];
            buf[k] = __builtin_nontemporal_load(xp + (size_t)(t0 + D + k) * CCH);

            // exact numpy op order: mul, mul, add (no FMA), then spike gate
            const float v = (w * xt) + (a * Vm);
            Vm = (Vm - 1.0f >= 0.0f) ? 0.0f : v;

            obuf[(k & 3) * CB + lane] = Vm;   // stage for transposed x4 store
            if ((k & 3) == 3) {
                const f32x4 vv = *(const f32x4*)&obuf[(lane >> 4) * CB + 4 * (lane & 15)];
                __builtin_nontemporal_store(
                    vv, (f32x4*)(go + (size_t)(t0 + (k - 3)) * CCH));
            }
        }
    }

    // Tail: last D steps, ring already holds x[T-D .. T-1]
#pragma unroll
    for (int k = 0; k < D; ++k) {
        const float xt = buf[k];
        const float v = (w * xt) + (a * Vm);
        Vm = (Vm - 1.0f >= 0.0f) ? 0.0f : v;

        obuf[(k & 3) * CB + lane] = Vm;
        if ((k & 3) == 3) {
            const f32x4 vv = *(const f32x4*)&obuf[(lane >> 4) * CB + 4 * (lane & 15)];
            __builtin_nontemporal_store(
                vv, (f32x4*)(go + (size_t)(T_STEPS - D + (k - 3)) * CCH));
        }
    }
}

extern "C" void kernel_launch(void* const* d_in, const int* in_sizes, int n_in,
                              void* d_out, int out_size, void* d_ws, size_t ws_size,
                              hipStream_t stream) {
    const float* x       = (const float*)d_in[0];
    const float* w_input = (const float*)d_in[1];
    const float* w_leak  = (const float*)d_in[2];
    float* out = (float*)d_out;

    dim3 grid(NSEQ * (CCH / CB));   // 512 blocks
    dim3 block(64);
    hipLaunchKernelGGL(lif_kernel, grid, block, 0, stream,
                       x, w_input, w_leak, out);
}

// Round 6
// 30.261 us; speedup vs baseline: 1.0352x; 1.0352x over previous
//
#include <hip/hip_runtime.h>

// LIF scan, x (B=32,G=4,T=512,C=256) f32 -> 32768 independent chains, T
// sequential (nonlinear recurrence). Memory-bound: 67 MB R + 67 MB W.
//
// R6: block = whole sequence (256 threads, 4 waves), 128 blocks.
//  - DRAM locality: loads of row t are one contiguous 1 KiB (4 waves x 256 B,
//    near-simultaneous); stores are full 1 KiB rows per dwordx4 instr, issued
//    as 8 KiB/wave bursts at window start. R5's pattern touched each 1 KiB
//    row 4x from 4 drifting CUs (row thrash) -> 4.3 TB/s effective.
//  - Register prefetch ring D=32 per thread (proven R3 load path).
//  - Double-buffered LDS out-window (2 x 32 steps x 1 KiB = 64 KB) for the
//    store transpose; barrier once per 32 steps.
//  - Raw s_barrier + lgkmcnt(0) only (NOT __syncthreads): does not drain
//    vmcnt, so the load ring stays in flight across windows.
//  - Exact simplified recurrence (R always {0,1}), contract off, numpy op
//    order: Vm' = (Vm >= 1) ? 0 : (w*xt + a*Vm).

typedef float f32x4 __attribute__((ext_vector_type(4)));

constexpr int T_STEPS = 512;
constexpr int CCH     = 256;
constexpr int NSEQ    = 128;            // B*G
constexpr int WIN     = 32;             // steps per window = ring depth
constexpr int NWIN    = T_STEPS / WIN;  // 16

__device__ __forceinline__ void window_barrier() {
    __builtin_amdgcn_sched_barrier(0);
    asm volatile("s_waitcnt lgkmcnt(0)" ::: "memory");
    __builtin_amdgcn_s_barrier();
    __builtin_amdgcn_sched_barrier(0);
}

__global__ __launch_bounds__(256, 1) void lif_kernel(
    const float* __restrict__ x,
    const float* __restrict__ w_input,
    const float* __restrict__ w_leak,
    float* __restrict__ out)
{
#pragma clang fp contract(off)
    __shared__ float obuf[2][WIN][CCH];     // 64 KB, double-buffered window

    const int j  = threadIdx.x;             // = channel
    const int wv = j >> 6;                  // wave 0..3
    const int l  = j & 63;
    const int n  = blockIdx.x;              // = sequence

    const float w = w_input[j];
    const float a = 1.0f - w_leak[j];

    const float* xp = x + (size_t)n * T_STEPS * CCH + j;
    // store base: this thread covers cols 4l..4l+3 of assigned rows
    float* ob = out + (size_t)n * T_STEPS * CCH + 4 * l;

    // Prime the ring: x[0..WIN-1]
    float buf[WIN];
#pragma unroll
    for (int k = 0; k < WIN; ++k) buf[k] = xp[(size_t)k * CCH];

    float Vm = 0.0f;

    // Store window [tbase..tbase+31] from obuf[p]: wave wv stores rows
    // s*4+wv (s=0..7), each instr = one contiguous 1 KiB row.
    auto do_stores = [&](int p, int tbase) {
#pragma unroll
        for (int s = 0; s < 8; ++s) {
            const int r = s * 4 + wv;
            const f32x4 vv = *(const f32x4*)&obuf[p][r][4 * l];
            *(f32x4*)(ob + (size_t)(tbase + r) * CCH) = vv;
        }
    };

    // Compute 32 steps into obuf[p]; refill ring for t0+WIN+k.
    auto do_window = [&](int p, int t0, bool refill) {
#pragma unroll
        for (int k = 0; k < WIN; ++k) {
            const float xt = buf[k];
            if (refill) buf[k] = xp[(size_t)(t0 + WIN + k) * CCH];
            // exact numpy op order: mul, mul, add (no FMA), then spike gate
            const float v = (w * xt) + (a * Vm);
            Vm = (Vm - 1.0f >= 0.0f) ? 0.0f : v;
            obuf[p][k][j] = Vm;             // ds_write, 2-way aliasing (free)
        }
    };

    do_window(0, 0, true);
    window_barrier();
    for (int W = 1; W < NWIN - 1; ++W) {
        do_stores((W - 1) & 1, (W - 1) * WIN);   // 8 KiB/wave write burst
        do_window(W & 1, W * WIN, true);
        window_barrier();
    }
    do_stores((NWIN - 2) & 1, (NWIN - 2) * WIN);
    do_window((NWIN - 1) & 1, (NWIN - 1) * WIN, false);
    window_barrier();
    do_stores((NWIN - 1) & 1, (NWIN - 1) * WIN);
}

extern "C" void kernel_launch(void* const* d_in, const int* in_sizes, int n_in,
                              void* d_out, int out_size, void* d_ws, size_t ws_size,
                              hipStream_t stream) {
    const float* x       = (const float*)d_in[0];
    const float* w_input = (const float*)d_in[1];
    const float* w_leak  = (const float*)d_in[2];
    float* out = (float*)d_out;

    dim3 grid(NSEQ);        // 128 blocks, block n = sequence n
    dim3 block(CCH);        // 256 threads = 4 waves
    hipLaunchKernelGGL(lif_kernel, grid, block, 0, stream,
                       x, w_input, w_leak, out);
}

// Round 7
// 28.067 us; speedup vs baseline: 1.1161x; 1.0782x over previous
//
#include <hip/hip_runtime.h>

// LIF scan, x (B=32,G=4,T=512,C=256) f32 -> 32768 chains, T sequential.
// Memory-bound: 67 MB R + 67 MB W.
//
// R7: strict R/W burst alternation (tests the interleave-granularity theory).
//  - Block = sequence n (256 threads, 4 waves), 128 blocks.
//  - x staged in 16-row (16 KiB contiguous) windows, triple-buffered in LDS
//    (48 KB), loaded 2 windows ahead via 4x global_load_lds_dwordx4.
//  - Compute: 16 steps; xt via ds_read_b32 (2-way alias, free); Vm chain in
//    registers; outputs accumulated in 16 statically-indexed registers.
//  - Store burst: 16 scalar dword stores back-to-back (wave = 256 B/instr,
//    block covers the full 16 KiB window) after compute, before the barrier.
//  - Exact counted vmcnt per window (in-order vmem retirement): steady 36.
//    Raw s_barrier only -- never drains vmcnt, bursts stay in flight.
//  - Recurrence bit-exact: contract off, v=(w*xt)+(a*Vm); Vm'=(Vm>=1)?0:v.

constexpr int T_STEPS = 512;
constexpr int CCH     = 256;
constexpr int NSEQ    = 128;
constexpr int WIN     = 16;
constexpr int NWIN    = T_STEPS / WIN;   // 32

__device__ __forceinline__ void sfence() { __builtin_amdgcn_sched_barrier(0); }

__global__ __launch_bounds__(256, 1) void lif_kernel(
    const float* __restrict__ x,
    const float* __restrict__ w_input,
    const float* __restrict__ w_leak,
    float* __restrict__ out)
{
#pragma clang fp contract(off)
    __shared__ float xw[3][WIN * CCH];   // 3 x 16 KiB x-windows

    const int tid = threadIdx.x;
    const int n   = blockIdx.x;

    const float w = w_input[tid];
    const float a = 1.0f - w_leak[tid];

    const float* xg = x   + (size_t)n * T_STEPS * CCH;
    float*       og = out + (size_t)n * T_STEPS * CCH + tid;

    // 16 KiB read burst for window Wt into buffer Wt%3.
    // Wave w's 4 instrs each DMA 1 KiB: LDS dest wave-uniform base + lane*16B,
    // global src per-lane; both linear -> xw[b][t'][c] = x[n, Wt*16+t', c].
    auto issue = [&](int Wt) {
        float* dst0 = &xw[Wt % 3][(tid >> 6) * 256];
        const float* src0 = xg + (size_t)Wt * (WIN * CCH) + tid * 4;
#pragma unroll
        for (int i = 0; i < 4; ++i) {
            __builtin_amdgcn_global_load_lds(
                (const __attribute__((address_space(1))) void*)(src0 + i * 1024),
                (__attribute__((address_space(3))) void*)(dst0 + i * 1024),
                16, 0, 0);
        }
        sfence();
    };

    float Vm = 0.0f;

    auto compute_store = [&](int Wt) {
        const float* xb = &xw[Wt % 3][0];
        float ov[WIN];                       // statically indexed -> registers
#pragma unroll
        for (int k = 0; k < WIN; ++k) {
            const float xt = xb[k * CCH + tid];
            // exact numpy op order: mul, mul, add (no FMA), then spike gate
            const float v = (w * xt) + (a * Vm);
            Vm = (Vm - 1.0f >= 0.0f) ? 0.0f : v;
            ov[k] = Vm;
        }
        sfence();
        // write burst: 16 back-to-back stores, block covers 16 KiB contiguous
#pragma unroll
        for (int k = 0; k < WIN; ++k)
            og[(size_t)(Wt * WIN + k) * CCH] = ov[k];
        sfence();
    };

    // Prologue: x[0], x[1] in flight; x[0] complete before compute 0.
    issue(0); issue(1);
    asm volatile("s_waitcnt vmcnt(4)" ::: "memory");   // x[0] done (x[1] after it)
    __builtin_amdgcn_s_barrier();

    // W = 0: after x[1]: x[2](4) + stores0(16) = 20
    issue(2);
    compute_store(0);
    asm volatile("s_waitcnt vmcnt(20)" ::: "memory");  // x[1] done
    __builtin_amdgcn_s_barrier();

    // W = 1..29 steady: after x[W+1]: stores(16) + loads(4) + stores(16) = 36
    for (int W = 1; W <= 29; ++W) {
        issue(W + 2);
        compute_store(W);
        asm volatile("s_waitcnt vmcnt(36)" ::: "memory");  // x[W+1] done
        __builtin_amdgcn_s_barrier();
    }

    // W = 30: no more issues; after x[31]: stores29(16) + stores30(16) = 32
    compute_store(30);
    asm volatile("s_waitcnt vmcnt(32)" ::: "memory");  // x[31] done
    __builtin_amdgcn_s_barrier();

    // W = 31
    compute_store(31);
}

extern "C" void kernel_launch(void* const* d_in, const int* in_sizes, int n_in,
                              void* d_out, int out_size, void* d_ws, size_t ws_size,
                              hipStream_t stream) {
    const float* x       = (const float*)d_in[0];
    const float* w_input = (const float*)d_in[1];
    const float* w_leak  = (const float*)d_in[2];
    float* out = (float*)d_out;

    dim3 grid(NSEQ);        // 128 blocks, block n = sequence n
    dim3 block(CCH);        // 256 threads = 4 waves
    hipLaunchKernelGGL(lif_kernel, grid, block, 0, stream,
                       x, w_input, w_leak, out);
}